// Round 1
// baseline (10668.242 us; speedup 1.0000x reference)
//
#include <hip/hip_runtime.h>
#include <math.h>
#include <stdint.h>

#define TT   512
#define BB   64
#define EMBD 300
#define NU   512
#define G3   1536   // 3*UNITS

static constexpr size_t XW_FLOATS = (size_t)2 * TT * BB * G3;   // 100,663,296
static constexpr size_t HB_FLOATS = (size_t)2 * 2 * BB * NU;    //     131,072

// ------------- embedding gather + input GEMM: xw[dir][t][b][c] -------------
__global__ __launch_bounds__(256) void k_input_gemm(
    const int* __restrict__ tokens, const float* __restrict__ emb,
    const float* __restrict__ Wf, const float* __restrict__ bf,
    const float* __restrict__ Wb, const float* __restrict__ bb,
    float* __restrict__ xw) {
  __shared__ float As[8][72];   // [k][b]
  __shared__ float Bs[8][64];   // [k][n]
  __shared__ int tok[64];
  const int t = blockIdx.y;
  const int n0 = blockIdx.x * 64;
  const int dir = blockIdx.z;
  const float* W = dir ? Wb : Wf;
  const float* bias = dir ? bb : bf;           // row 0 = input bias
  float* out = xw + (size_t)dir * TT * BB * G3;
  const int tid = threadIdx.x;
  if (tid < 64) tok[tid] = tokens[(size_t)tid * TT + t];
  __syncthreads();
  const int tx = tid & 15, ty = tid >> 4;
  float4 c0 = {0,0,0,0}, c1 = {0,0,0,0}, c2 = {0,0,0,0}, c3 = {0,0,0,0};
  for (int kc = 0; kc < 38; ++kc) {
    const int k0 = kc * 8;
    if (tid < 128) {
      int kb = tid >> 4, nq = (tid & 15) * 4;
      float4 v = {0,0,0,0};
      if (k0 + kb < EMBD) v = *(const float4*)(W + (size_t)(k0 + kb) * G3 + n0 + nq);
      *(float4*)&Bs[kb][nq] = v;
    } else {
      int th = tid - 128;
      int b = th >> 1, kh = (th & 1) * 4;
      float4 v = {0,0,0,0};
      if (k0 + kh + 4 <= EMBD) v = *(const float4*)(emb + (size_t)tok[b] * EMBD + k0 + kh);
      As[kh + 0][b] = v.x; As[kh + 1][b] = v.y; As[kh + 2][b] = v.z; As[kh + 3][b] = v.w;
    }
    __syncthreads();
    #pragma unroll
    for (int kb = 0; kb < 8; ++kb) {
      float4 bv = *(const float4*)&Bs[kb][tx * 4];
      float4 av = *(const float4*)&As[kb][ty * 4];
      c0.x = fmaf(av.x, bv.x, c0.x); c0.y = fmaf(av.x, bv.y, c0.y);
      c0.z = fmaf(av.x, bv.z, c0.z); c0.w = fmaf(av.x, bv.w, c0.w);
      c1.x = fmaf(av.y, bv.x, c1.x); c1.y = fmaf(av.y, bv.y, c1.y);
      c1.z = fmaf(av.y, bv.z, c1.z); c1.w = fmaf(av.y, bv.w, c1.w);
      c2.x = fmaf(av.z, bv.x, c2.x); c2.y = fmaf(av.z, bv.y, c2.y);
      c2.z = fmaf(av.z, bv.z, c2.z); c2.w = fmaf(av.z, bv.w, c2.w);
      c3.x = fmaf(av.w, bv.x, c3.x); c3.y = fmaf(av.w, bv.y, c3.y);
      c3.z = fmaf(av.w, bv.z, c3.z); c3.w = fmaf(av.w, bv.w, c3.w);
    }
    __syncthreads();
  }
  float4 bi = *(const float4*)(bias + n0 + tx * 4);
  size_t base = ((size_t)t * BB + (size_t)ty * 4) * G3 + n0 + tx * 4;
  float4 o;
  o.x = c0.x + bi.x; o.y = c0.y + bi.y; o.z = c0.z + bi.z; o.w = c0.w + bi.w;
  *(float4*)(out + base) = o;
  o.x = c1.x + bi.x; o.y = c1.y + bi.y; o.z = c1.z + bi.z; o.w = c1.w + bi.w;
  *(float4*)(out + base + G3) = o;
  o.x = c2.x + bi.x; o.y = c2.y + bi.y; o.z = c2.z + bi.z; o.w = c2.w + bi.w;
  *(float4*)(out + base + 2 * G3) = o;
  o.x = c3.x + bi.x; o.y = c3.y + bi.y; o.z = c3.z + bi.z; o.w = c3.w + bi.w;
  *(float4*)(out + base + 3 * G3) = o;
}

// --------------------------- persistent GRU scan v2 ---------------------------
// 512 blocks = 16 sync-groups (dir x bblk, 8 batches each) x 32 ublk (16 units).
// 2 blocks/CU (GUARANTEED by __launch_bounds__(256,2): VGPR<=256, LDS 42.5KB;
// capacity = 256*2 = 512 = grid, so all groups fully resident -> no deadlock).
// XOR role map: any two wg's at offset 1/16/256 are in DIFFERENT groups, so the
// co-resident partner block computes while this one spins -> sync latency hidden.
// U slice is 16 units wide -> 96 VGPRs/thread, pinned via empty asm.
// Thread = (u in 16, ks in 16 of 32k); 8 batches accumulated in regs.
__global__ __launch_bounds__(256, 2) void k_gru(
    const float* __restrict__ xw,
    const float* __restrict__ Uf, const float* __restrict__ Ub,
    const float* __restrict__ bf, const float* __restrict__ bb,
    float* __restrict__ hbuf, int* __restrict__ ctr,
    float* __restrict__ out, float* __restrict__ state) {
  __shared__ float hS[8][NU];           // h for 8 batches, XOR-swizzled columns
  __shared__ float red[3][8][17][16];   // [gate][batch][ksplit(pad17)][unit]
  const int wg = blockIdx.x;
  const int lo4 = wg & 15, mid4 = (wg >> 4) & 15, hi1 = wg >> 8;
  const int gid  = lo4 ^ mid4 ^ (hi1 ? 15 : 0);   // group: dir(1b) | bblk(3b)
  const int ublk = (hi1 << 4) | mid4;             // 0..31
  const int dir  = gid >> 3;
  const int bblk = gid & 7;
  const int u0 = ublk * 16, b0 = bblk * 8;
  int* gctr = ctr + gid * 32;                     // 128B-spaced counters
  const int tid = threadIdx.x;
  const int u  = tid & 15;             // unit within slice (compute phase)
  const int ks = tid >> 4;             // ksplit 0..15 (32 k each)
  const int kb0 = ks * 32;
  const int swzb = (ks & 7) << 2;      // per-thread hS column swizzle bits
  const float* xwd = xw + (size_t)dir * TT * BB * G3;
  const float* U = dir ? Ub : Uf;      // [k][c], c = gate*512 + unit
  const float* br = (dir ? bb : bf) + G3;   // row 1 = recurrent bias
  float* hb = hbuf + (size_t)dir * 2 * BB * NU;

  // ---- preload U slice (k in [kb0,kb0+32), col u0+u) into regs, then PIN ----
  float Uz_r[32], Ur_r[32], Uh_r[32];
  #pragma unroll
  for (int kk = 0; kk < 32; ++kk) {
    const float* row = U + (size_t)(kb0 + kk) * G3 + u0 + u;
    Uz_r[kk] = row[0];
    Ur_r[kk] = row[512];
    Uh_r[kk] = row[1024];
  }
  #pragma unroll
  for (int kk = 0; kk < 32; ++kk) {
    asm volatile("" : "+v"(Uz_r[kk]), "+v"(Ur_r[kk]), "+v"(Uh_r[kk]));
  }

  // epilogue role: tid<128 -> (eb, eu) output element; h_prev kept in a reg
  const int eb = tid >> 4;   // valid as batch only for tid<128
  const int eu = tid & 15;
  float brz = 0.f, brr = 0.f, brh = 0.f, hprev = 0.f;
  float xz = 0.f, xr = 0.f, xh = 0.f;
  if (tid < 128) {
    brz = br[u0 + eu]; brr = br[512 + u0 + eu]; brh = br[1024 + u0 + eu];
    const int t0 = dir ? (TT - 1) : 0;
    const float* xp = xwd + ((size_t)t0 * BB + b0 + eb) * G3 + u0 + eu;
    xz = xp[0]; xr = xp[512]; xh = xp[1024];
  }

  float* hflat = &hS[0][0];
  #pragma unroll
  for (int j = 0; j < 16; ++j) hflat[tid + j * 256] = 0.f;   // h0 = 0
  __syncthreads();

  for (int s = 0; s < TT; ++s) {
    const int t = dir ? (TT - 1 - s) : s;
    float az[8], ar[8], ah[8];
    #pragma unroll
    for (int b = 0; b < 8; ++b) { az[b] = 0.f; ar[b] = 0.f; ah[b] = 0.f; }
    #pragma unroll
    for (int q = 0; q < 8; ++q) {
      const int col = kb0 + ((q << 2) ^ swzb);   // swizzled -> 4 addrs, 4 bank-quads
      #pragma unroll
      for (int b = 0; b < 8; ++b) {
        float4 hv = *(const float4*)&hS[b][col];   // 16-lane broadcast
        az[b] = fmaf(Uz_r[q*4+0], hv.x, az[b]); az[b] = fmaf(Uz_r[q*4+1], hv.y, az[b]);
        az[b] = fmaf(Uz_r[q*4+2], hv.z, az[b]); az[b] = fmaf(Uz_r[q*4+3], hv.w, az[b]);
        ar[b] = fmaf(Ur_r[q*4+0], hv.x, ar[b]); ar[b] = fmaf(Ur_r[q*4+1], hv.y, ar[b]);
        ar[b] = fmaf(Ur_r[q*4+2], hv.z, ar[b]); ar[b] = fmaf(Ur_r[q*4+3], hv.w, ar[b]);
        ah[b] = fmaf(Uh_r[q*4+0], hv.x, ah[b]); ah[b] = fmaf(Uh_r[q*4+1], hv.y, ah[b]);
        ah[b] = fmaf(Uh_r[q*4+2], hv.z, ah[b]); ah[b] = fmaf(Uh_r[q*4+3], hv.w, ah[b]);
      }
    }
    #pragma unroll
    for (int b = 0; b < 8; ++b) {
      red[0][b][ks][u] = az[b];
      red[1][b][ks][u] = ar[b];
      red[2][b][ks][u] = ah[b];
    }
    __syncthreads();
    float hn = 0.f;
    if (tid < 128) {
      float rz = 0.f, rr = 0.f, rh = 0.f;
      #pragma unroll
      for (int q2 = 0; q2 < 16; ++q2) {
        rz += red[0][eb][q2][eu];
        rr += red[1][eb][q2][eu];
        rh += red[2][eb][q2][eu];
      }
      const float z  = 1.f / (1.f + __expf(-(xz + rz + brz)));
      const float r  = 1.f / (1.f + __expf(-(xr + rr + brr)));
      const float hh = tanhf(xh + r * (rh + brh));
      hn = z * hprev + (1.f - z) * hh;
      hprev = hn;
      // h exchange: agent-scope (LLC-coherent) store, bypasses per-XCD L2
      __hip_atomic_store(hb + ((size_t)(s & 1) * BB + b0 + eb) * NU + u0 + eu, hn,
                         __ATOMIC_RELAXED, __HIP_MEMORY_SCOPE_AGENT);
      // streaming store: keep L2 clean so the release-wbl2 has nothing to flush
      __builtin_nontemporal_store(
          hn, out + ((size_t)(b0 + eb) * TT + t) * 1024 + (size_t)dir * NU + u0 + eu);
    }
    if (s == TT - 1) {
      if (tid < 128)
        state[(size_t)(b0 + eb) * 1024 + (size_t)dir * NU + u0 + eu] = hn;
    } else {
      // prefetch next step's xw NOW: its HBM latency hides under the spin
      if (tid < 128) {
        const int tn = dir ? (TT - 2 - s) : (s + 1);
        const float* xp = xwd + ((size_t)tn * BB + b0 + eb) * G3 + u0 + eu;
        xz = xp[0]; xr = xp[512]; xh = xp[1024];
      }
      __syncthreads();   // all lanes' h stores drained (vmcnt in barrier)
      if (tid == 0) {
        // RELEASE: drains vmcnt + wbl2 before the add becomes visible
        __hip_atomic_fetch_add(gctr, 1, __ATOMIC_RELEASE, __HIP_MEMORY_SCOPE_AGENT);
        const int target = 32 * (s + 1);
        while (__hip_atomic_load(gctr, __ATOMIC_RELAXED, __HIP_MEMORY_SCOPE_AGENT) < target) {
          __builtin_amdgcn_s_sleep(2);
        }
      }
      __syncthreads();
      // reload h for our 8 batches, all 512 units (16 KB): 8 x u64 bypass loads
      const uint64_t* hsrc = (const uint64_t*)(hb + (size_t)(s & 1) * BB * NU);
      #pragma unroll
      for (int j = 0; j < 8; ++j) {
        const int fi = tid + j * 256;          // u64 index in [0,2048)
        const int bl = fi >> 8;                // batch 0..7
        const int k2 = fi & 255;               // u64 within row
        const int k  = k2 * 2;
        uint64_t v = __hip_atomic_load(hsrc + ((size_t)(b0 + bl) << 8) + k2,
                                       __ATOMIC_RELAXED, __HIP_MEMORY_SCOPE_AGENT);
        const int c = k ^ (((k >> 5) & 7) << 2);   // swizzled column (pair-safe)
        *(uint64_t*)&hS[bl][c] = v;
      }
      __syncthreads();
    }
  }
}

extern "C" void kernel_launch(void* const* d_in, const int* in_sizes, int n_in,
                              void* d_out, int out_size, void* d_ws, size_t ws_size,
                              hipStream_t stream) {
  (void)in_sizes; (void)n_in; (void)out_size; (void)ws_size;
  const int*   tokens = (const int*)d_in[0];
  const float* emb    = (const float*)d_in[1];
  const float* Wf     = (const float*)d_in[2];
  const float* Uf     = (const float*)d_in[3];
  const float* bf     = (const float*)d_in[4];
  const float* Wb     = (const float*)d_in[5];
  const float* Ub     = (const float*)d_in[6];
  const float* bb     = (const float*)d_in[7];
  float* ws = (float*)d_ws;
  float* xw = ws;
  float* hb = ws + XW_FLOATS;
  int*   ctr = (int*)(hb + HB_FLOATS);
  float* out = (float*)d_out;
  float* state = out + (size_t)BB * TT * 1024;

  hipMemsetAsync(ctr, 0, 16 * 32 * sizeof(int), stream);
  hipLaunchKernelGGL(k_input_gemm, dim3(24, 512, 2), dim3(256), 0, stream,
                     tokens, emb, Wf, bf, Wb, bb, xw);
  hipLaunchKernelGGL(k_gru, dim3(512), dim3(256), 0, stream,
                     xw, Uf, Ub, bf, bb, hb, ctr, out, state);
}

// Round 3
// 7748.960 us; speedup vs baseline: 1.3767x; 1.3767x over previous
//
#include <hip/hip_runtime.h>
#include <math.h>
#include <stdint.h>

#define TT   512
#define BB   64
#define EMBD 300
#define NU   512
#define G3   1536   // 3*UNITS

static constexpr size_t XW_FLOATS = (size_t)2 * TT * BB * G3;   // 100,663,296
static constexpr size_t HB_FLOATS = (size_t)2 * 2 * BB * NU;    //     131,072

// ------------- embedding gather + input GEMM: xw[dir][t][b][c] -------------
__global__ __launch_bounds__(256) void k_input_gemm(
    const int* __restrict__ tokens, const float* __restrict__ emb,
    const float* __restrict__ Wf, const float* __restrict__ bf,
    const float* __restrict__ Wb, const float* __restrict__ bb,
    float* __restrict__ xw) {
  __shared__ float As[8][72];   // [k][b]
  __shared__ float Bs[8][64];   // [k][n]
  __shared__ int tok[64];
  const int t = blockIdx.y;
  const int n0 = blockIdx.x * 64;
  const int dir = blockIdx.z;
  const float* W = dir ? Wb : Wf;
  const float* bias = dir ? bb : bf;           // row 0 = input bias
  float* out = xw + (size_t)dir * TT * BB * G3;
  const int tid = threadIdx.x;
  if (tid < 64) tok[tid] = tokens[(size_t)tid * TT + t];
  __syncthreads();
  const int tx = tid & 15, ty = tid >> 4;
  float4 c0 = {0,0,0,0}, c1 = {0,0,0,0}, c2 = {0,0,0,0}, c3 = {0,0,0,0};
  for (int kc = 0; kc < 38; ++kc) {
    const int k0 = kc * 8;
    if (tid < 128) {
      int kb = tid >> 4, nq = (tid & 15) * 4;
      float4 v = {0,0,0,0};
      if (k0 + kb < EMBD) v = *(const float4*)(W + (size_t)(k0 + kb) * G3 + n0 + nq);
      *(float4*)&Bs[kb][nq] = v;
    } else {
      int th = tid - 128;
      int b = th >> 1, kh = (th & 1) * 4;
      float4 v = {0,0,0,0};
      if (k0 + kh + 4 <= EMBD) v = *(const float4*)(emb + (size_t)tok[b] * EMBD + k0 + kh);
      As[kh + 0][b] = v.x; As[kh + 1][b] = v.y; As[kh + 2][b] = v.z; As[kh + 3][b] = v.w;
    }
    __syncthreads();
    #pragma unroll
    for (int kb = 0; kb < 8; ++kb) {
      float4 bv = *(const float4*)&Bs[kb][tx * 4];
      float4 av = *(const float4*)&As[kb][ty * 4];
      c0.x = fmaf(av.x, bv.x, c0.x); c0.y = fmaf(av.x, bv.y, c0.y);
      c0.z = fmaf(av.x, bv.z, c0.z); c0.w = fmaf(av.x, bv.w, c0.w);
      c1.x = fmaf(av.y, bv.x, c1.x); c1.y = fmaf(av.y, bv.y, c1.y);
      c1.z = fmaf(av.y, bv.z, c1.z); c1.w = fmaf(av.y, bv.w, c1.w);
      c2.x = fmaf(av.z, bv.x, c2.x); c2.y = fmaf(av.z, bv.y, c2.y);
      c2.z = fmaf(av.z, bv.z, c2.z); c2.w = fmaf(av.z, bv.w, c2.w);
      c3.x = fmaf(av.w, bv.x, c3.x); c3.y = fmaf(av.w, bv.y, c3.y);
      c3.z = fmaf(av.w, bv.z, c3.z); c3.w = fmaf(av.w, bv.w, c3.w);
    }
    __syncthreads();
  }
  float4 bi = *(const float4*)(bias + n0 + tx * 4);
  size_t base = ((size_t)t * BB + (size_t)ty * 4) * G3 + n0 + tx * 4;
  float4 o;
  o.x = c0.x + bi.x; o.y = c0.y + bi.y; o.z = c0.z + bi.z; o.w = c0.w + bi.w;
  *(float4*)(out + base) = o;
  o.x = c1.x + bi.x; o.y = c1.y + bi.y; o.z = c1.z + bi.z; o.w = c1.w + bi.w;
  *(float4*)(out + base + G3) = o;
  o.x = c2.x + bi.x; o.y = c2.y + bi.y; o.z = c2.z + bi.z; o.w = c2.w + bi.w;
  *(float4*)(out + base + 2 * G3) = o;
  o.x = c3.x + bi.x; o.y = c3.y + bi.y; o.z = c3.z + bi.z; o.w = c3.w + bi.w;
  *(float4*)(out + base + 3 * G3) = o;
}

// --------------------------- persistent GRU scan v4 ---------------------------
// 128 blocks x 512 threads = dir(2) x batchpair(4, 16 batches) x ublk(16).
// Each block carries TWO batch-groups (A: 8 batches, B: 8 batches) over the
// SAME register-resident U slice (32 units, 96 VGPRs, asm-pinned).
// One super-iteration advances BOTH groups one step -> ONE release store +
// ONE poll per 2 GRU-steps (sync amortized 2x vs v1; wbl2 rate 4x lower).
// v3 post-mortem: relaxed flag stores are NOT correct (barrier vmcnt-drain
// does not publish h cross-XCD; the release's buffer_wbl2 is load-bearing).
// Signal = release STORE to a private slot (no RMW serialization).
// Epilogues for A and B run in parallel on thread halves (512 = 2x8x32).
__global__ __launch_bounds__(512, 1) void k_gru(
    const float* __restrict__ xw,
    const float* __restrict__ Uf, const float* __restrict__ Ub,
    const float* __restrict__ bf, const float* __restrict__ bb,
    float* __restrict__ hbuf, int* __restrict__ ctr,
    float* __restrict__ out, float* __restrict__ state) {
  __shared__ float hS[16][NU];            // 32KB: h for 16 batches (A:0-7, B:8-15)
  __shared__ float redA[3][8][16][32];    // 48KB  [gate][b][ksplit][unit]
  __shared__ float redB[3][8][16][32];    // 48KB
  const int wg   = blockIdx.x;            // 0..127
  const int dir  = wg >> 6;
  const int P    = (wg >> 4) & 3;         // batch-pair: batches P*16 .. P*16+15
  const int ublk = wg & 15;
  const int u0  = ublk * 32;
  const int bA0 = P * 16;
  const int pg  = dir * 4 + P;            // pair-group id (8 total)
  int* flags = ctr + pg * 16;             // 16 member flags = one 64B line
  const int tid = threadIdx.x;
  const int u  = tid & 31;                // unit (compute phase)
  const int ks = tid >> 5;                // ksplit 0..15 (32 k each)
  const int kb0 = ks * 32;
  const float* xwd = xw + (size_t)dir * TT * BB * G3;
  const float* U = dir ? Ub : Uf;         // [k][c], c = gate*512 + unit
  const float* br = (dir ? bb : bf) + G3; // row 1 = recurrent bias
  float* hb = hbuf + (size_t)dir * 2 * BB * NU;   // [parity][64][512]

  // ---- preload U slice (k in [kb0,kb0+32), col u0+u) into regs, then PIN ----
  float Uz_r[32], Ur_r[32], Uh_r[32];
  #pragma unroll
  for (int kk = 0; kk < 32; ++kk) {
    const float* row = U + (size_t)(kb0 + kk) * G3 + u0 + u;
    Uz_r[kk] = row[0];
    Ur_r[kk] = row[512];
    Uh_r[kk] = row[1024];
  }
  #pragma unroll
  for (int kk = 0; kk < 32; ++kk) {
    asm volatile("" : "+v"(Uz_r[kk]), "+v"(Ur_r[kk]), "+v"(Uh_r[kk]));
  }

  // epilogue identity: half 0 = group A (tids 0..255), half 1 = group B
  const int half = tid >> 8;
  const int et = tid & 255;
  const int eb = et >> 5, eu = et & 31;
  const int bg = bA0 + half * 8 + eb;     // global batch this thread finalizes
  const float brz = br[u0 + eu], brr = br[512 + u0 + eu], brh = br[1024 + u0 + eu];
  float xz, xr, xh;
  {
    const int t0 = dir ? (TT - 1) : 0;
    const float* xp = xwd + ((size_t)t0 * BB + bg) * G3 + u0 + eu;
    xz = xp[0]; xr = xp[512]; xh = xp[1024];
  }

  float* hflat = &hS[0][0];
  #pragma unroll
  for (int j = 0; j < 16; ++j) hflat[tid + j * 512] = 0.f;   // h0 = 0
  __syncthreads();

  for (int s = 0; s < TT; ++s) {
    const int t = dir ? (TT - 1 - s) : s;
    // ---------------- compute A (batches bA0..bA0+7) ----------------
    {
      float az[8], ar[8], ah[8];
      #pragma unroll
      for (int b = 0; b < 8; ++b) { az[b] = 0.f; ar[b] = 0.f; ah[b] = 0.f; }
      #pragma unroll
      for (int q = 0; q < 8; ++q) {
        #pragma unroll
        for (int b = 0; b < 8; ++b) {
          float4 hv = *(const float4*)&hS[b][kb0 + q * 4];   // 2-addr broadcast
          az[b] = fmaf(Uz_r[q*4+0], hv.x, az[b]); az[b] = fmaf(Uz_r[q*4+1], hv.y, az[b]);
          az[b] = fmaf(Uz_r[q*4+2], hv.z, az[b]); az[b] = fmaf(Uz_r[q*4+3], hv.w, az[b]);
          ar[b] = fmaf(Ur_r[q*4+0], hv.x, ar[b]); ar[b] = fmaf(Ur_r[q*4+1], hv.y, ar[b]);
          ar[b] = fmaf(Ur_r[q*4+2], hv.z, ar[b]); ar[b] = fmaf(Ur_r[q*4+3], hv.w, ar[b]);
          ah[b] = fmaf(Uh_r[q*4+0], hv.x, ah[b]); ah[b] = fmaf(Uh_r[q*4+1], hv.y, ah[b]);
          ah[b] = fmaf(Uh_r[q*4+2], hv.z, ah[b]); ah[b] = fmaf(Uh_r[q*4+3], hv.w, ah[b]);
        }
      }
      #pragma unroll
      for (int b = 0; b < 8; ++b) {
        redA[0][b][ks][u] = az[b];
        redA[1][b][ks][u] = ar[b];
        redA[2][b][ks][u] = ah[b];
      }
    }
    // ---------------- compute B (batches bA0+8..bA0+15) ----------------
    {
      float az[8], ar[8], ah[8];
      #pragma unroll
      for (int b = 0; b < 8; ++b) { az[b] = 0.f; ar[b] = 0.f; ah[b] = 0.f; }
      #pragma unroll
      for (int q = 0; q < 8; ++q) {
        #pragma unroll
        for (int b = 0; b < 8; ++b) {
          float4 hv = *(const float4*)&hS[8 + b][kb0 + q * 4];
          az[b] = fmaf(Uz_r[q*4+0], hv.x, az[b]); az[b] = fmaf(Uz_r[q*4+1], hv.y, az[b]);
          az[b] = fmaf(Uz_r[q*4+2], hv.z, az[b]); az[b] = fmaf(Uz_r[q*4+3], hv.w, az[b]);
          ar[b] = fmaf(Ur_r[q*4+0], hv.x, ar[b]); ar[b] = fmaf(Ur_r[q*4+1], hv.y, ar[b]);
          ar[b] = fmaf(Ur_r[q*4+2], hv.z, ar[b]); ar[b] = fmaf(Ur_r[q*4+3], hv.w, ar[b]);
          ah[b] = fmaf(Uh_r[q*4+0], hv.x, ah[b]); ah[b] = fmaf(Uh_r[q*4+1], hv.y, ah[b]);
          ah[b] = fmaf(Uh_r[q*4+2], hv.z, ah[b]); ah[b] = fmaf(Uh_r[q*4+3], hv.w, ah[b]);
        }
      }
      #pragma unroll
      for (int b = 0; b < 8; ++b) {
        redB[0][b][ks][u] = az[b];
        redB[1][b][ks][u] = ar[b];
        redB[2][b][ks][u] = ah[b];
      }
    }
    __syncthreads();
    // ---------------- epilogue: A on tids 0..255, B on 256..511 ----------------
    const float (*red)[8][16][32] = half ? redB : redA;
    float rz = 0.f, rr = 0.f, rh = 0.f;
    #pragma unroll
    for (int q2 = 0; q2 < 16; ++q2) {
      rz += red[0][eb][q2][eu];
      rr += red[1][eb][q2][eu];
      rh += red[2][eb][q2][eu];
    }
    const float z  = 1.f / (1.f + __expf(-(xz + rz + brz)));
    const float r  = 1.f / (1.f + __expf(-(xr + rr + brr)));
    const float hh = tanhf(xh + r * (rh + brh));
    const float hold = hS[half * 8 + eb][u0 + eu];
    const float hn = z * hold + (1.f - z) * hh;
    // h exchange: agent-scope atomic store (v1-proven path)
    __hip_atomic_store(hb + ((size_t)(s & 1) * BB + bg) * NU + u0 + eu, hn,
                       __ATOMIC_RELAXED, __HIP_MEMORY_SCOPE_AGENT);
    out[((size_t)bg * TT + t) * 1024 + (size_t)dir * NU + u0 + eu] = hn;
    if (s == TT - 1) {
      state[(size_t)bg * 1024 + (size_t)dir * NU + u0 + eu] = hn;
    } else {
      // prefetch next step's xw: HBM latency hides under the sync window
      {
        const int tn = dir ? (TT - 2 - s) : (s + 1);
        const float* xp = xwd + ((size_t)tn * BB + bg) * G3 + u0 + eu;
        xz = xp[0]; xr = xp[512]; xh = xp[1024];
      }
      __syncthreads();   // all 512 threads' h-stores vmcnt-drained
      if (tid == 0) {
        // RELEASE store: wbl2 publishes this XCD's h data, THEN flag lands.
        // Private slot -> 16 parallel releases, no RMW serialization.
        __hip_atomic_store(flags + ublk, s + 1,
                           __ATOMIC_RELEASE, __HIP_MEMORY_SCOPE_AGENT);
      }
      // wave 0 polls all 16 member flags (one coalesced 64B load per round)
      if (tid < 64) {
        const int target = s + 1;
        int f = target;
        for (;;) {
          if (tid < 16)
            f = __hip_atomic_load(flags + tid, __ATOMIC_RELAXED,
                                  __HIP_MEMORY_SCOPE_AGENT);
          if (__all(f >= target)) break;
          __builtin_amdgcn_s_sleep(1);
        }
      }
      __syncthreads();
      // reload h for 16 batches, all 512 units (32 KB): 8 x u64 bypass loads
      const uint64_t* hsrc =
          (const uint64_t*)(hb + (size_t)(s & 1) * BB * NU) + ((size_t)bA0 << 8);
      #pragma unroll
      for (int j = 0; j < 8; ++j) {
        const int fi = tid + j * 512;          // u64 index in [0,4096)
        const int bl = fi >> 8;                // local batch 0..15
        const int k2 = fi & 255;               // u64 within row
        uint64_t v = __hip_atomic_load(hsrc + ((size_t)bl << 8) + k2,
                                       __ATOMIC_RELAXED, __HIP_MEMORY_SCOPE_AGENT);
        *(uint64_t*)&hS[bl][k2 * 2] = v;
      }
      __syncthreads();
    }
  }
}

extern "C" void kernel_launch(void* const* d_in, const int* in_sizes, int n_in,
                              void* d_out, int out_size, void* d_ws, size_t ws_size,
                              hipStream_t stream) {
  (void)in_sizes; (void)n_in; (void)out_size; (void)ws_size;
  const int*   tokens = (const int*)d_in[0];
  const float* emb    = (const float*)d_in[1];
  const float* Wf     = (const float*)d_in[2];
  const float* Uf     = (const float*)d_in[3];
  const float* bf     = (const float*)d_in[4];
  const float* Wb     = (const float*)d_in[5];
  const float* Ub     = (const float*)d_in[6];
  const float* bb     = (const float*)d_in[7];
  float* ws = (float*)d_ws;
  float* xw = ws;
  float* hb = ws + XW_FLOATS;
  int*   ctr = (int*)(hb + HB_FLOATS);
  float* out = (float*)d_out;
  float* state = out + (size_t)BB * TT * 1024;

  hipMemsetAsync(ctr, 0, 16 * 32 * sizeof(int), stream);
  hipLaunchKernelGGL(k_input_gemm, dim3(24, 512, 2), dim3(256), 0, stream,
                     tokens, emb, Wf, bf, Wb, bb, xw);
  hipLaunchKernelGGL(k_gru, dim3(128), dim3(512), 0, stream,
                     xw, Uf, Ub, bf, bb, hb, ctr, out, state);
}